// Round 16
// baseline (140.183 us; speedup 1.0000x reference)
//
#include <hip/hip_runtime.h>

// Problem constants (fixed by the reference).
constexpr int IN_CH = 4;
constexpr int KS    = 40;
constexpr int L_IN  = 8192;
constexpr int L_OUT = L_IN - KS + 1;   // 8153
constexpr int NF    = 600;
constexpr int BATCH = 32;

typedef float floatx4  __attribute__((ext_vector_type(4)));                 // 16B-aligned (stores)
typedef float floatx4u __attribute__((ext_vector_type(4), aligned(4)));     // 4B-aligned (reads)

// One block per output row (19200 blocks = max store parallelism), single
// dispatch (R15: fusing tap extraction saved ~24us of graph-edge drain).
// Reads straight from x via unaligned dwordx4 (x = 4 MB, L2-resident on every
// XCD under any dispatch mapping). NT stores (evict-first through L2: write
// aggregation without evicting x; worth -16us vs plain, confirmed twice).
// R16 single-variable change vs R15: XCD swizzle REMOVED (row = bid) -- its
// rationale (phase-table L2 residency) died in R13; linear mapping gives the
// co-resident block window one contiguous sliding write span.
__global__ __launch_bounds__(256) void fdc_row(const float* __restrict__ x,
                                               const float* __restrict__ w,
                                               float* __restrict__ out) {
    const int row = blockIdx.x;            // 0..19199 == b*NF + k (linear, no swizzle)
    const int b   = row / NF;
    const int k   = row - b * NF;

    // ---- per-block tap extraction (all waves redundant; uniform result) ----
    const float* wk  = w + (size_t)k * IN_CH * KS;   // 160 floats
    const int    lane = threadIdx.x & 63;
    const float  a0 = wk[lane];
    const float  a1 = wk[lane + 64];
    const float  a2 = (lane < 32) ? wk[lane + 128] : 0.0f;   // guard k=599 OOB
    const unsigned long long m0 = __ballot(a0 != 0.0f);
    const unsigned long long m1 = __ballot(a1 != 0.0f);
    const unsigned long long m2 = __ballot(a2 != 0.0f);
    int i0, i1;
    if (m0)      i0 = __builtin_ctzll(m0);
    else if (m1) i0 = 64 + __builtin_ctzll(m1);
    else         i0 = 128 + __builtin_ctzll(m2);
    if (m2)      i1 = 128 + 63 - __builtin_clzll(m2);
    else if (m1) i1 = 64 + 63 - __builtin_clzll(m1);
    else         i1 = 63 - __builtin_clzll(m0);
    const float w0 = wk[i0];                          // uniform scalar loads
    const float w1 = wk[i1];

    const float* xb = x + (size_t)b * IN_CH * L_IN;
    const float* x0 = xb + (i0 / KS) * L_IN + (i0 % KS);
    const float* x1 = xb + (i1 / KS) * L_IN + (i1 % KS);

    const size_t e0   = (size_t)row * L_OUT;
    float*       orow = out + e0;
    const int    a    = (int)((0u - (unsigned)e0) & 15u);  // head elems to 64B boundary
    const int    n4   = (L_OUT - a) >> 2;                  // aligned float4s (~2036)
    const int    tail = L_OUT - a - (n4 << 2);             // <= 3

#pragma unroll 2
    for (int t = threadIdx.x; t < n4; t += 256) {
        const int l = a + t * 4;
        const floatx4u v0 = *reinterpret_cast<const floatx4u*>(x0 + l);
        const floatx4u v1 = *reinterpret_cast<const floatx4u*>(x1 + l);
        floatx4 v;
        v.x = w0 * v0.x + w1 * v1.x;
        v.y = w0 * v0.y + w1 * v1.y;
        v.z = w0 * v0.z + w1 * v1.z;
        v.w = w0 * v0.w + w1 * v1.w;
        __builtin_nontemporal_store(v, reinterpret_cast<floatx4*>(orow + l));
    }

    // head [0,a) + tail [a+4*n4, L_OUT): <= 18 scalars, once per block
    if (threadIdx.x < 24) {
        int elem = -1;
        if ((int)threadIdx.x < a) {
            elem = (int)threadIdx.x;
        } else {
            const int rr = (int)threadIdx.x - a;
            if (rr < tail) elem = a + (n4 << 2) + rr;
        }
        if (elem >= 0) orow[elem] = w0 * x0[elem] + w1 * x1[elem];
    }
}

extern "C" void kernel_launch(void* const* d_in, const int* in_sizes, int n_in,
                              void* d_out, int out_size, void* d_ws, size_t ws_size,
                              hipStream_t stream) {
    const float* x = (const float*)d_in[0];   // [32, 4, 8192] fp32
    const float* w = (const float*)d_in[1];   // [600, 4, 40]  fp32
    float*       o = (float*)d_out;           // [32, 600, 8153] fp32
    (void)d_ws; (void)ws_size;

    fdc_row<<<NF * BATCH, 256, 0, stream>>>(x, w, o);   // single dispatch
}

// Round 17
// 122.368 us; speedup vs baseline: 1.1456x; 1.1456x over previous
//
#include <hip/hip_runtime.h>

// Problem constants (fixed by the reference).
constexpr int IN_CH = 4;
constexpr int KS    = 40;
constexpr int L_IN  = 8192;
constexpr int L_OUT = L_IN - KS + 1;   // 8153
constexpr int NF    = 600;
constexpr int BATCH = 32;
constexpr int HLEN  = 4080;            // first-half length (64B multiple); 2nd = 4073
constexpr int RPX   = NF * BATCH / 8;  // 2400 rows per XCD slice

typedef float floatx4  __attribute__((ext_vector_type(4)));                 // 16B-aligned (stores)
typedef float floatx4u __attribute__((ext_vector_type(4), aligned(4)));     // 4B-aligned (reads)

// R17 = R15 (best, 124.8us: XCD swizzle + NT stores + direct L2 reads +
// fused ballot tap extraction + single dispatch) with one change: each row is
// split into TWO half-row blocks (38400 blocks), mapped so each XCD still
// writes its 78 MB slice strictly sequentially (idx>>1 = row, idx&1 = half).
// Probes store-stream granularity at fixed XCD-sequentiality (R6->R8/R11:
// more blocks monotonically better so far).
__global__ __launch_bounds__(256) void fdc_half(const float* __restrict__ x,
                                                const float* __restrict__ w,
                                                float* __restrict__ out) {
    const int bid  = blockIdx.x;            // 0..38399
    const int xcd  = bid & 7;
    const int idx  = bid >> 3;              // 0..4799, sequential within XCD
    const int half = idx & 1;
    const int row  = xcd * RPX + (idx >> 1);
    const int b    = row / NF;
    const int k    = row - b * NF;

    // ---- per-block tap extraction (all waves redundant; uniform result) ----
    const float* wk  = w + (size_t)k * IN_CH * KS;   // 160 floats
    const int    lane = threadIdx.x & 63;
    const float  a0 = wk[lane];
    const float  a1 = wk[lane + 64];
    const float  a2 = (lane < 32) ? wk[lane + 128] : 0.0f;   // guard k=599 OOB
    const unsigned long long m0 = __ballot(a0 != 0.0f);
    const unsigned long long m1 = __ballot(a1 != 0.0f);
    const unsigned long long m2 = __ballot(a2 != 0.0f);
    int i0, i1;
    if (m0)      i0 = __builtin_ctzll(m0);
    else if (m1) i0 = 64 + __builtin_ctzll(m1);
    else         i0 = 128 + __builtin_ctzll(m2);
    if (m2)      i1 = 128 + 63 - __builtin_clzll(m2);
    else if (m1) i1 = 64 + 63 - __builtin_clzll(m1);
    else         i1 = 63 - __builtin_clzll(m0);
    const float w0 = wk[i0];                          // uniform scalar loads
    const float w1 = wk[i1];

    const int off = half ? HLEN : 0;
    const int len = half ? (L_OUT - HLEN) : HLEN;

    const float* xb = x + (size_t)b * IN_CH * L_IN;
    const float* x0 = xb + (i0 / KS) * L_IN + (i0 % KS) + off;
    const float* x1 = xb + (i1 / KS) * L_IN + (i1 % KS) + off;

    const size_t s0   = (size_t)row * L_OUT + off;    // element offset of span
    float*       orow = out + s0;
    const int    a    = (int)((0u - (unsigned)s0) & 15u);  // head elems to 64B boundary
    const int    n4   = (len - a) >> 2;                    // aligned float4s (<=1020)
    const int    tail = len - a - (n4 << 2);               // <= 3

#pragma unroll 2
    for (int t = threadIdx.x; t < n4; t += 256) {
        const int l = a + t * 4;
        const floatx4u v0 = *reinterpret_cast<const floatx4u*>(x0 + l);
        const floatx4u v1 = *reinterpret_cast<const floatx4u*>(x1 + l);
        floatx4 v;
        v.x = w0 * v0.x + w1 * v1.x;
        v.y = w0 * v0.y + w1 * v1.y;
        v.z = w0 * v0.z + w1 * v1.z;
        v.w = w0 * v0.w + w1 * v1.w;
        __builtin_nontemporal_store(v, reinterpret_cast<floatx4*>(orow + l));
    }

    // head [0,a) + tail [a+4*n4, len): <= 18 scalars, once per block
    if (threadIdx.x < 24) {
        int elem = -1;
        if ((int)threadIdx.x < a) {
            elem = (int)threadIdx.x;
        } else {
            const int rr = (int)threadIdx.x - a;
            if (rr < tail) elem = a + (n4 << 2) + rr;
        }
        if (elem >= 0) orow[elem] = w0 * x0[elem] + w1 * x1[elem];
    }
}

extern "C" void kernel_launch(void* const* d_in, const int* in_sizes, int n_in,
                              void* d_out, int out_size, void* d_ws, size_t ws_size,
                              hipStream_t stream) {
    const float* x = (const float*)d_in[0];   // [32, 4, 8192] fp32
    const float* w = (const float*)d_in[1];   // [600, 4, 40]  fp32
    float*       o = (float*)d_out;           // [32, 600, 8153] fp32
    (void)d_ws; (void)ws_size;

    fdc_half<<<NF * BATCH * 2, 256, 0, stream>>>(x, w, o);   // 38400 half-row blocks
}

// Round 18
// 119.681 us; speedup vs baseline: 1.1713x; 1.0225x over previous
//
#include <hip/hip_runtime.h>

// Problem constants (fixed by the reference).
constexpr int IN_CH = 4;
constexpr int KS    = 40;
constexpr int L_IN  = 8192;
constexpr int L_OUT = L_IN - KS + 1;   // 8153
constexpr int NF    = 600;
constexpr int BATCH = 32;
constexpr int QLEN  = 2048;            // quarter length (64B multiple); last = 2009
constexpr int RPX   = NF * BATCH / 8;  // 2400 rows per XCD slice

typedef float floatx4  __attribute__((ext_vector_type(4)));                 // 16B-aligned (stores)
typedef float floatx4u __attribute__((ext_vector_type(4), aligned(4)));     // 4B-aligned (reads)

// R18 = R17 (122.4us best) with one change: quarter-row blocks (76800),
// idx>>2 = row-in-slice, idx&3 = quarter -> per-XCD address walk stays
// strictly sequential. Final granularity probe (19200->38400 gave -2.4us).
__global__ __launch_bounds__(256) void fdc_quart(const float* __restrict__ x,
                                                 const float* __restrict__ w,
                                                 float* __restrict__ out) {
    const int bid   = blockIdx.x;           // 0..76799
    const int xcd   = bid & 7;
    const int idx   = bid >> 3;             // 0..9599, sequential within XCD
    const int quart = idx & 3;
    const int row   = xcd * RPX + (idx >> 2);
    const int b     = row / NF;
    const int k     = row - b * NF;

    // ---- per-block tap extraction (all waves redundant; uniform result) ----
    const float* wk  = w + (size_t)k * IN_CH * KS;   // 160 floats
    const int    lane = threadIdx.x & 63;
    const float  a0 = wk[lane];
    const float  a1 = wk[lane + 64];
    const float  a2 = (lane < 32) ? wk[lane + 128] : 0.0f;   // guard k=599 OOB
    const unsigned long long m0 = __ballot(a0 != 0.0f);
    const unsigned long long m1 = __ballot(a1 != 0.0f);
    const unsigned long long m2 = __ballot(a2 != 0.0f);
    int i0, i1;
    if (m0)      i0 = __builtin_ctzll(m0);
    else if (m1) i0 = 64 + __builtin_ctzll(m1);
    else         i0 = 128 + __builtin_ctzll(m2);
    if (m2)      i1 = 128 + 63 - __builtin_clzll(m2);
    else if (m1) i1 = 64 + 63 - __builtin_clzll(m1);
    else         i1 = 63 - __builtin_clzll(m0);
    const float w0 = wk[i0];                          // uniform scalar loads
    const float w1 = wk[i1];

    const int off = quart * QLEN;
    const int len = (quart == 3) ? (L_OUT - 3 * QLEN) : QLEN;

    const float* xb = x + (size_t)b * IN_CH * L_IN;
    const float* x0 = xb + (i0 / KS) * L_IN + (i0 % KS) + off;
    const float* x1 = xb + (i1 / KS) * L_IN + (i1 % KS) + off;

    const size_t s0   = (size_t)row * L_OUT + off;    // element offset of span
    float*       orow = out + s0;
    const int    a    = (int)((0u - (unsigned)s0) & 15u);  // head elems to 64B boundary
    const int    n4   = (len - a) >> 2;                    // aligned float4s (<=512)
    const int    tail = len - a - (n4 << 2);               // <= 3

#pragma unroll 2
    for (int t = threadIdx.x; t < n4; t += 256) {
        const int l = a + t * 4;
        const floatx4u v0 = *reinterpret_cast<const floatx4u*>(x0 + l);
        const floatx4u v1 = *reinterpret_cast<const floatx4u*>(x1 + l);
        floatx4 v;
        v.x = w0 * v0.x + w1 * v1.x;
        v.y = w0 * v0.y + w1 * v1.y;
        v.z = w0 * v0.z + w1 * v1.z;
        v.w = w0 * v0.w + w1 * v1.w;
        __builtin_nontemporal_store(v, reinterpret_cast<floatx4*>(orow + l));
    }

    // head [0,a) + tail [a+4*n4, len): <= 18 scalars, once per block
    if (threadIdx.x < 24) {
        int elem = -1;
        if ((int)threadIdx.x < a) {
            elem = (int)threadIdx.x;
        } else {
            const int rr = (int)threadIdx.x - a;
            if (rr < tail) elem = a + (n4 << 2) + rr;
        }
        if (elem >= 0) orow[elem] = w0 * x0[elem] + w1 * x1[elem];
    }
}

extern "C" void kernel_launch(void* const* d_in, const int* in_sizes, int n_in,
                              void* d_out, int out_size, void* d_ws, size_t ws_size,
                              hipStream_t stream) {
    const float* x = (const float*)d_in[0];   // [32, 4, 8192] fp32
    const float* w = (const float*)d_in[1];   // [600, 4, 40]  fp32
    float*       o = (float*)d_out;           // [32, 600, 8153] fp32
    (void)d_ws; (void)ws_size;

    fdc_quart<<<NF * BATCH * 4, 256, 0, stream>>>(x, w, o);   // 76800 quarter-row blocks
}

// Round 19
// 112.242 us; speedup vs baseline: 1.2489x; 1.0663x over previous
//
#include <hip/hip_runtime.h>

// Problem constants (fixed by the reference).
constexpr int IN_CH = 4;
constexpr int KS    = 40;
constexpr int L_IN  = 8192;
constexpr int L_OUT = L_IN - KS + 1;   // 8153
constexpr int NF    = 600;
constexpr int BATCH = 32;
constexpr int ELEN  = 1024;            // eighth length (64B multiple); last = 985
constexpr int RPX   = NF * BATCH / 8;  // 2400 rows per XCD slice

typedef float floatx4  __attribute__((ext_vector_type(4)));                 // 16B-aligned (stores)
typedef float floatx4u __attribute__((ext_vector_type(4), aligned(4)));     // 4B-aligned (reads)

// R19 = R18 (119.7us best) with one change: eighth-row blocks (153600).
// idx>>3 = row-in-slice, idx&7 = eighth -> per-XCD walk stays sequential.
// Each thread now stores EXACTLY one float4 (no loop). Granularity ladder:
// 19200 = 124.8, 38400 = 122.4, 76800 = 119.7 us.
__global__ __launch_bounds__(256) void fdc_eighth(const float* __restrict__ x,
                                                  const float* __restrict__ w,
                                                  float* __restrict__ out) {
    const int bid    = blockIdx.x;          // 0..153599
    const int xcd    = bid & 7;
    const int idx    = bid >> 3;            // 0..19199, sequential within XCD
    const int eighth = idx & 7;
    const int row    = xcd * RPX + (idx >> 3);
    const int b      = row / NF;
    const int k      = row - b * NF;

    // ---- per-block tap extraction (all waves redundant; uniform result) ----
    const float* wk  = w + (size_t)k * IN_CH * KS;   // 160 floats
    const int    lane = threadIdx.x & 63;
    const float  a0 = wk[lane];
    const float  a1 = wk[lane + 64];
    const float  a2 = (lane < 32) ? wk[lane + 128] : 0.0f;   // guard k=599 OOB
    const unsigned long long m0 = __ballot(a0 != 0.0f);
    const unsigned long long m1 = __ballot(a1 != 0.0f);
    const unsigned long long m2 = __ballot(a2 != 0.0f);
    int i0, i1;
    if (m0)      i0 = __builtin_ctzll(m0);
    else if (m1) i0 = 64 + __builtin_ctzll(m1);
    else         i0 = 128 + __builtin_ctzll(m2);
    if (m2)      i1 = 128 + 63 - __builtin_clzll(m2);
    else if (m1) i1 = 64 + 63 - __builtin_clzll(m1);
    else         i1 = 63 - __builtin_clzll(m0);
    const float w0 = wk[i0];                          // uniform scalar loads
    const float w1 = wk[i1];

    const int off = eighth * ELEN;
    const int len = (eighth == 7) ? (L_OUT - 7 * ELEN) : ELEN;

    const float* xb = x + (size_t)b * IN_CH * L_IN;
    const float* x0 = xb + (i0 / KS) * L_IN + (i0 % KS) + off;
    const float* x1 = xb + (i1 / KS) * L_IN + (i1 % KS) + off;

    const size_t s0   = (size_t)row * L_OUT + off;    // element offset of span
    float*       orow = out + s0;
    const int    a    = (int)((0u - (unsigned)s0) & 15u);  // head elems to 64B boundary
    const int    n4   = (len - a) >> 2;                    // aligned float4s (<=256)
    const int    tail = len - a - (n4 << 2);               // <= 3

    const int t = threadIdx.x;
    if (t < n4) {                                          // exactly one float4/thread
        const int l = a + t * 4;
        const floatx4u v0 = *reinterpret_cast<const floatx4u*>(x0 + l);
        const floatx4u v1 = *reinterpret_cast<const floatx4u*>(x1 + l);
        floatx4 v;
        v.x = w0 * v0.x + w1 * v1.x;
        v.y = w0 * v0.y + w1 * v1.y;
        v.z = w0 * v0.z + w1 * v1.z;
        v.w = w0 * v0.w + w1 * v1.w;
        __builtin_nontemporal_store(v, reinterpret_cast<floatx4*>(orow + l));
    }

    // head [0,a) + tail [a+4*n4, len): <= 18 scalars, lanes 232..255
    const unsigned hidx = (unsigned)t - 232u;
    if (hidx < 24u) {
        int elem = -1;
        if ((int)hidx < a) {
            elem = (int)hidx;
        } else {
            const int rr = (int)hidx - a;
            if (rr < tail) elem = a + (n4 << 2) + rr;
        }
        if (elem >= 0) orow[elem] = w0 * x0[elem] + w1 * x1[elem];
    }
}

extern "C" void kernel_launch(void* const* d_in, const int* in_sizes, int n_in,
                              void* d_out, int out_size, void* d_ws, size_t ws_size,
                              hipStream_t stream) {
    const float* x = (const float*)d_in[0];   // [32, 4, 8192] fp32
    const float* w = (const float*)d_in[1];   // [600, 4, 40]  fp32
    float*       o = (float*)d_out;           // [32, 600, 8153] fp32
    (void)d_ws; (void)ws_size;

    fdc_eighth<<<NF * BATCH * 8, 256, 0, stream>>>(x, w, o);   // 153600 eighth-row blocks
}